// Round 5
// baseline (42.840 us; speedup 1.0000x reference)
//
#include <hip/hip_runtime.h>
#include <math.h>

#define TPB 256
#define NQ 2                  // matrices per thread, paired in v2 lanes
#define CHUNK (TPB * NQ)      // matrices per block

typedef float v2  __attribute__((ext_vector_type(2)));
typedef int   v2i __attribute__((ext_vector_type(2)));
typedef float f2g __attribute__((ext_vector_type(2), aligned(8)));  // global float2

static __device__ __forceinline__ v2 V2(float x){ v2 r; r.x=x; r.y=x; return r; }
static __device__ __forceinline__ v2 vfma(v2 a, v2 b, v2 c){ return __builtin_elementwise_fma(a, b, c); }
static __device__ __forceinline__ v2 vmax(v2 a, v2 b){ return __builtin_elementwise_max(a, b); }
static __device__ __forceinline__ v2 vabs(v2 a){ return __builtin_elementwise_abs(a); }
static __device__ __forceinline__ v2 vcps(v2 a, v2 b){ return __builtin_elementwise_copysign(a, b); }

static __device__ __forceinline__ v2 rsq2(v2 x){ v2 r; r.x=__builtin_amdgcn_rsqf(x.x);  r.y=__builtin_amdgcn_rsqf(x.y);  return r; }
static __device__ __forceinline__ v2 rcp2(v2 x){ v2 r; r.x=__builtin_amdgcn_rcpf(x.x);  r.y=__builtin_amdgcn_rcpf(x.y);  return r; }
static __device__ __forceinline__ v2 sqt2(v2 x){ v2 r; r.x=__builtin_amdgcn_sqrtf(x.x); r.y=__builtin_amdgcn_sqrtf(x.y); return r; }
static __device__ __forceinline__ v2 lg22(v2 x){ v2 r; r.x=__builtin_amdgcn_logf(x.x);  r.y=__builtin_amdgcn_logf(x.y);  return r; }
static __device__ __forceinline__ v2 ex22(v2 x){ v2 r; r.x=__builtin_amdgcn_exp2f(x.x); r.y=__builtin_amdgcn_exp2f(x.y); return r; }

static __device__ __forceinline__ v2 vsel(v2i m, v2 a, v2 b){
  v2i ai = __builtin_bit_cast(v2i, a), bi = __builtin_bit_cast(v2i, b);
  return __builtin_bit_cast(v2, bi ^ ((ai ^ bi) & m));
}

// Exact Jacobi rotation for [[app,apq],[apq,aqq]] via half-angle form.
// 1e-30f clamp is a representable normal: degenerate case -> identity, NaN-free.
__device__ __forceinline__ void jcs2(v2 app_in, v2 aqq_in, v2 apq,
                                     v2& c, v2& s,
                                     v2& app_out, v2& aqq_out)
{
  v2 d    = (aqq_in - app_in) * 0.5f;
  v2 r2   = vmax(vfma(d, d, apq * apq), V2(1e-30f));
  v2 invh = rsq2(r2);
  v2 h    = r2 * invh;                       // sqrt(d^2 + apq^2)
  v2 sg   = vcps(V2(1.0f), d);
  v2 ch   = h + vabs(d);
  v2 sh   = apq * sg;
  v2 w    = rsq2(vfma(ch, ch, sh * sh));
  c = ch * w;
  s = sh * w;
  v2 hs = h * sg;
  v2 m  = app_in + d;
  app_out = m - hs;
  aqq_out = m + hs;
}

__device__ __forceinline__ void jrot(v2& app, v2& aqq, v2& apq,
                                     v2& apk, v2& aqk,
                                     v2& vp0, v2& vp1, v2& vp2,
                                     v2& vq0, v2& vq1, v2& vq2)
{
  v2 c, s;
  jcs2(app, aqq, apq, c, s, app, aqq);
  apq = V2(0.0f);
  v2 pk = apk, qk = aqk;
  apk = c * pk - s * qk;
  aqk = s * pk + c * qk;
  v2 v;
  v = vp0; vp0 = c*v - s*vq0; vq0 = s*v + c*vq0;
  v = vp1; vp1 = c*v - s*vq1; vq1 = s*v + c*vq1;
  v = vp2; vp2 = c*v - s*vq2; vq2 = s*v + c*vq2;
}

#define CSWAP(li, lj, a0, a1, a2, b0, b1, b2)                                   \
  do {                                                                          \
    v2i _m = (li) < (lj);                                                       \
    v2 _t;                                                                      \
    _t = vsel(_m,(lj),(li)); (lj) = vsel(_m,(li),(lj)); (li) = _t;              \
    _t = vsel(_m,(b0),(a0)); (b0) = vsel(_m,(a0),(b0)); (a0) = _t;              \
    _t = vsel(_m,(b1),(a1)); (b1) = vsel(_m,(a1),(b1)); (a1) = _t;              \
    _t = vsel(_m,(b2),(a2)); (b2) = vsel(_m,(a2),(b2)); (a2) = _t;              \
  } while (0)

__global__ __launch_bounds__(TPB) void plastic_svd_kernel(
    const float* __restrict__ F,
    const float* __restrict__ p_yml,
    const float* __restrict__ p_nu,
    const float* __restrict__ p_ys,
    float* __restrict__ out,
    int nmat)
{
  // Thread-PRIVATE F scratch (write-own/read-own: NO barriers in this kernel).
  // Column-major [9][TPB]: ds b64 lane-stride = 2 banks -> 2 lanes/bank (free).
  __shared__ v2 sf[9][TPB];
  const int tid = threadIdx.x;
  const int u   = blockIdx.x * TPB + tid;      // thread id
  const int m0  = 2 * u;                       // first matrix of the pair
  if (m0 >= nmat) return;
  const bool full = (m0 + 1 < nmat);

  // ---- direct global loads: 9 x float2 (72B span, 8B-aligned) ----
  v2 f00,f01,f02,f10,f11,f12,f20,f21,f22;
  if (full) {
    const f2g* gp = (const f2g*)(F + (size_t)m0 * 9);
    f2g r0=gp[0], r1=gp[1], r2=gp[2], r3=gp[3], r4=gp[4],
        r5=gp[5], r6=gp[6], r7=gp[7], r8=gp[8];
    // mem[0..8]=matrix m0 row-major, mem[9..17]=matrix m0+1; pair components
    f00.x=r0.x; f00.y=r4.y;   // mem0 , mem9
    f01.x=r0.y; f01.y=r5.x;   // mem1 , mem10
    f02.x=r1.x; f02.y=r5.y;
    f10.x=r1.y; f10.y=r6.x;
    f11.x=r2.x; f11.y=r6.y;
    f12.x=r2.y; f12.y=r7.x;
    f20.x=r3.x; f20.y=r7.y;
    f21.x=r3.y; f21.y=r8.x;
    f22.x=r4.x; f22.y=r8.y;
  } else {                                     // odd tail: duplicate matrix
    const float* p = F + (size_t)m0 * 9;
    f00=V2(p[0]); f01=V2(p[1]); f02=V2(p[2]);
    f10=V2(p[3]); f11=V2(p[4]); f12=V2(p[5]);
    f20=V2(p[6]); f21=V2(p[7]); f22=V2(p[8]);
  }

  // uniform scalar parameters
  const float mu_s = __builtin_amdgcn_exp2f(p_yml[0] * 1.44269504f) *
                     __builtin_amdgcn_rcpf(2.0f * (1.0f + p_nu[0]));
  const float qy_s = p_ys[0] * 0.5f * __builtin_amdgcn_rcpf(mu_s);
  const v2 qy = V2(qy_s);

  // ---- S = F^T F ----
  v2 s00 = f00*f00 + f10*f10 + f20*f20;
  v2 s11 = f01*f01 + f11*f11 + f21*f21;
  v2 s22 = f02*f02 + f12*f12 + f22*f22;
  v2 s01 = f00*f01 + f10*f11 + f20*f21;
  v2 s02 = f00*f02 + f10*f12 + f20*f22;
  v2 s12 = f01*f02 + f11*f12 + f21*f22;

  // ---- park F in private LDS scratch (regs die -> low pressure in Jacobi) ----
  sf[0][tid]=f00; sf[1][tid]=f01; sf[2][tid]=f02;
  sf[3][tid]=f10; sf[4][tid]=f11; sf[5][tid]=f12;
  sf[6][tid]=f20; sf[7][tid]=f21; sf[8][tid]=f22;

  v2 v00,v01,v02,v10,v11,v12,v20,v21,v22;
  v2 c, s;

  // ---- sweep 1, rot (0,1): V = I specialization ----
  jcs2(s00, s11, s01, c, s, s00, s11);
  { v2 pk = s02, qk = s12; s02 = c*pk - s*qk; s12 = s*pk + c*qk; }
  v00 = c;  v01 = s;
  v10 = -s; v11 = c;
  s01 = V2(0.0f);
  // ---- sweep 1, rot (0,2): col2 still e3, col0 = (v00,v10,0) ----
  jcs2(s00, s22, s02, c, s, s00, s22);
  { v2 pk = s01, qk = s12; s01 = c*pk - s*qk; s12 = s*pk + c*qk; }
  v02 = s * v00; v12 = s * v10; v22 = c;
  v00 = c * v00; v10 = c * v10; v20 = -s;
  v21 = V2(0.0f);
  s02 = V2(0.0f);
  // ---- sweep 1, rot (1,2) ----
  jrot(s11, s22, s12, s01, s02, v01, v11, v21, v02, v12, v22);
  // ---- sweep 2 ----
  jrot(s00, s11, s01, s02, s12, v00, v10, v20, v01, v11, v21);
  jrot(s00, s22, s02, s01, s12, v00, v10, v20, v02, v12, v22);
  jrot(s11, s22, s12, s01, s02, v01, v11, v21, v02, v12, v22);
  // ---- sweep 3 ----
  jrot(s00, s11, s01, s02, s12, v00, v10, v20, v01, v11, v21);
  jrot(s00, s22, s02, s01, s12, v00, v10, v20, v02, v12, v22);
  // final rot (1,2): couplings dead; diag still updated (closed form).
  jcs2(s11, s22, s12, c, s, s11, s22);
  { v2 v;
    v = v01; v01 = c*v - s*v02; v02 = s*v + c*v02;
    v = v11; v11 = c*v - s*v12; v12 = s*v + c*v12;
    v = v21; v21 = c*v - s*v22; v22 = s*v + c*v22; }

  // ---- sort eigenvalues descending (GS conditioning: R2 lesson) ----
  v2 l0 = s00, l1 = s11, l2 = s22;
  CSWAP(l0, l1, v00, v10, v20, v01, v11, v21);
  CSWAP(l1, l2, v01, v11, v21, v02, v12, v22);
  CSWAP(l0, l1, v00, v10, v20, v01, v11, v21);

  // ---- restore F from private scratch ----
  f00=sf[0][tid]; f01=sf[1][tid]; f02=sf[2][tid];
  f10=sf[3][tid]; f11=sf[4][tid]; f12=sf[5][tid];
  f20=sf[6][tid]; f21=sf[7][tid]; f22=sf[8][tid];

  // ---- U: u0 = Fv0/|Fv0|; u1 = GS; u2 = u0 x u1 (sign-fixed) ----
  v2 w0x = f00*v00 + f01*v10 + f02*v20;
  v2 w0y = f10*v00 + f11*v10 + f12*v20;
  v2 w0z = f20*v00 + f21*v10 + f22*v20;
  v2 n0sq = w0x*w0x + w0y*w0y + w0z*w0z;
  v2 inv0 = rsq2(vmax(n0sq, V2(1e-30f)));
  v2 u0x = w0x*inv0, u0y = w0y*inv0, u0z = w0z*inv0;

  v2 w1x = f00*v01 + f01*v11 + f02*v21;
  v2 w1y = f10*v01 + f11*v11 + f12*v21;
  v2 w1z = f20*v01 + f21*v11 + f22*v21;
  v2 n1sq_pre = w1x*w1x + w1y*w1y + w1z*w1z;  // = sigma1^2 (pre-GS)
  v2 d01 = w1x*u0x + w1y*u0y + w1z*u0z;
  w1x = w1x - d01*u0x; w1y = w1y - d01*u0y; w1z = w1z - d01*u0z;
  v2 n1sq = w1x*w1x + w1y*w1y + w1z*w1z;
  v2 inv1 = rsq2(vmax(n1sq, V2(1e-30f)));
  v2 u1x = w1x*inv1, u1y = w1y*inv1, u1z = w1z*inv1;

  v2 u2x = u0y*u1z - u0z*u1y;
  v2 u2y = u0z*u1x - u0x*u1z;
  v2 u2z = u0x*u1y - u0y*u1x;
  v2 w2x = f00*v02 + f01*v12 + f02*v22;
  v2 w2y = f10*v02 + f11*v12 + f12*v22;
  v2 w2z = f20*v02 + f21*v12 + f22*v22;
  v2 s2d = u2x*w2x + u2y*w2y + u2z*w2z;
  v2 sg = vcps(V2(1.0f), s2d);               // sign-fix for det(U)=+1
  v2 sig2 = vabs(s2d);
  u2x = u2x * sg; u2y = u2y * sg; u2z = u2z * sg;

  // ---- von-Mises return mapping, base-2 internally ----
  // max(sqrt(n),0.01) == sqrt(max(n,1e-4)) -> e = 0.5*log2(max(n,1e-4))
  v2 e0 = lg22(vmax(n0sq,     V2(1e-4f))) * 0.5f;
  v2 e1 = lg22(vmax(n1sq_pre, V2(1e-4f))) * 0.5f;
  v2 e2 = lg22(vmax(sig2,     V2(0.01f)));
  v2 m3 = (e0 + e1 + e2) * (1.0f / 3.0f);
  v2 b0 = e0 - m3, b1 = e1 - m3, b2 = e2 - m3;
  v2 bn = sqt2(b0*b0 + b1*b1 + b2*b2) * 0.69314718f + V2(1e-5f);
  v2 r = vmax(bn - qy, V2(0.0f)) * rcp2(bn);   // 0 if elastic
  v2 c0 = ex22(e0 - r * b0);
  v2 c1 = ex22(e1 - r * b1);
  v2 c2 = ex22(e2 - r * b2);

  // ---- out = sum_i c_i u_i v_i^T ----
  v2 a0x = c0*u0x, a0y = c0*u0y, a0z = c0*u0z;
  v2 a1x = c1*u1x, a1y = c1*u1y, a1z = c1*u1z;
  v2 a2x = c2*u2x, a2y = c2*u2y, a2z = c2*u2z;

  v2 o00 = a0x*v00 + a1x*v01 + a2x*v02;
  v2 o01 = a0x*v10 + a1x*v11 + a2x*v12;
  v2 o02 = a0x*v20 + a1x*v21 + a2x*v22;
  v2 o10 = a0y*v00 + a1y*v01 + a2y*v02;
  v2 o11 = a0y*v10 + a1y*v11 + a2y*v12;
  v2 o12 = a0y*v20 + a1y*v21 + a2y*v22;
  v2 o20 = a0z*v00 + a1z*v01 + a2z*v02;
  v2 o21 = a0z*v10 + a1z*v11 + a2z*v12;
  v2 o22 = a0z*v20 + a1z*v21 + a2z*v22;

  // ---- direct global stores: 9 x float2 ----
  if (full) {
    f2g* op = (f2g*)(out + (size_t)m0 * 9);
    f2g w0={o00.x,o01.x}, w1={o02.x,o10.x}, w2={o11.x,o12.x},
        w3={o20.x,o21.x}, w4={o22.x,o00.y}, w5={o01.y,o02.y},
        w6={o10.y,o11.y}, w7={o12.y,o20.y}, w8={o21.y,o22.y};
    op[0]=w0; op[1]=w1; op[2]=w2; op[3]=w3; op[4]=w4;
    op[5]=w5; op[6]=w6; op[7]=w7; op[8]=w8;
  } else {
    float* p = out + (size_t)m0 * 9;
    p[0]=o00.x; p[1]=o01.x; p[2]=o02.x;
    p[3]=o10.x; p[4]=o11.x; p[5]=o12.x;
    p[6]=o20.x; p[7]=o21.x; p[8]=o22.x;
  }
}

extern "C" void kernel_launch(void* const* d_in, const int* in_sizes, int n_in,
                              void* d_out, int out_size, void* d_ws, size_t ws_size,
                              hipStream_t stream) {
  const float* F     = (const float*)d_in[0];
  const float* p_yml = (const float*)d_in[1];
  const float* p_nu  = (const float*)d_in[2];
  const float* p_ys  = (const float*)d_in[3];
  float* out = (float*)d_out;

  const int nmat = in_sizes[0] / 9;
  const int nblocks = (nmat + CHUNK - 1) / CHUNK;
  hipLaunchKernelGGL(plastic_svd_kernel, dim3(nblocks), dim3(TPB), 0, stream,
                     F, p_yml, p_nu, p_ys, out, nmat);
}

// Round 6
// 33.360 us; speedup vs baseline: 1.2842x; 1.2842x over previous
//
#include <hip/hip_runtime.h>
#include <math.h>

#define TPB 64                // ONE WAVE per workgroup: __syncthreads is a
                              // waitcnt-only fence, no barrier resource, up to
                              // 32 single-wave WGs resident per CU.
#define NQ 2                  // matrices per thread, paired in v2 lanes
#define CHUNK (TPB * NQ)      // 128 matrices per block
#define CH_F (CHUNK * 9)      // 1152 floats per block
#define CH_F4 (CH_F / 4)      // 288 float4 per block

typedef float v2  __attribute__((ext_vector_type(2)));
typedef int   v2i __attribute__((ext_vector_type(2)));

static __device__ __forceinline__ v2 V2(float x){ v2 r; r.x=x; r.y=x; return r; }
static __device__ __forceinline__ v2 vfma(v2 a, v2 b, v2 c){ return __builtin_elementwise_fma(a, b, c); }
static __device__ __forceinline__ v2 vmax(v2 a, v2 b){ return __builtin_elementwise_max(a, b); }
static __device__ __forceinline__ v2 vabs(v2 a){ return __builtin_elementwise_abs(a); }
static __device__ __forceinline__ v2 vcps(v2 a, v2 b){ return __builtin_elementwise_copysign(a, b); }

static __device__ __forceinline__ v2 rsq2(v2 x){ v2 r; r.x=__builtin_amdgcn_rsqf(x.x);  r.y=__builtin_amdgcn_rsqf(x.y);  return r; }
static __device__ __forceinline__ v2 rcp2(v2 x){ v2 r; r.x=__builtin_amdgcn_rcpf(x.x);  r.y=__builtin_amdgcn_rcpf(x.y);  return r; }
static __device__ __forceinline__ v2 sqt2(v2 x){ v2 r; r.x=__builtin_amdgcn_sqrtf(x.x); r.y=__builtin_amdgcn_sqrtf(x.y); return r; }
static __device__ __forceinline__ v2 lg22(v2 x){ v2 r; r.x=__builtin_amdgcn_logf(x.x);  r.y=__builtin_amdgcn_logf(x.y);  return r; }
static __device__ __forceinline__ v2 ex22(v2 x){ v2 r; r.x=__builtin_amdgcn_exp2f(x.x); r.y=__builtin_amdgcn_exp2f(x.y); return r; }

// elementwise select via 3-op xor form (pattern-matches to v_cndmask)
static __device__ __forceinline__ v2 vsel(v2i m, v2 a, v2 b){
  v2i ai = __builtin_bit_cast(v2i, a), bi = __builtin_bit_cast(v2i, b);
  return __builtin_bit_cast(v2, bi ^ ((ai ^ bi) & m));
}

// Exact Jacobi rotation for [[app,apq],[apq,aqq]] via half-angle form.
// 1e-30f clamp is a representable normal: degenerate case -> identity, NaN-free.
__device__ __forceinline__ void jcs2(v2 app_in, v2 aqq_in, v2 apq,
                                     v2& c, v2& s,
                                     v2& app_out, v2& aqq_out)
{
  v2 d    = (aqq_in - app_in) * 0.5f;
  v2 r2   = vmax(vfma(d, d, apq * apq), V2(1e-30f));
  v2 invh = rsq2(r2);
  v2 h    = r2 * invh;                       // sqrt(d^2 + apq^2)
  v2 sg   = vcps(V2(1.0f), d);
  v2 ch   = h + vabs(d);
  v2 sh   = apq * sg;
  v2 w    = rsq2(vfma(ch, ch, sh * sh));
  c = ch * w;
  s = sh * w;
  v2 hs = h * sg;
  v2 m  = app_in + d;
  app_out = m - hs;
  aqq_out = m + hs;
}

__device__ __forceinline__ void jrot(v2& app, v2& aqq, v2& apq,
                                     v2& apk, v2& aqk,
                                     v2& vp0, v2& vp1, v2& vp2,
                                     v2& vq0, v2& vq1, v2& vq2)
{
  v2 c, s;
  jcs2(app, aqq, apq, c, s, app, aqq);
  apq = V2(0.0f);
  v2 pk = apk, qk = aqk;
  apk = c * pk - s * qk;
  aqk = s * pk + c * qk;
  v2 v;
  v = vp0; vp0 = c*v - s*vq0; vq0 = s*v + c*vq0;
  v = vp1; vp1 = c*v - s*vq1; vq1 = s*v + c*vq1;
  v = vp2; vp2 = c*v - s*vq2; vq2 = s*v + c*vq2;
}

#define CSWAP(li, lj, a0, a1, a2, b0, b1, b2)                                   \
  do {                                                                          \
    v2i _m = (li) < (lj);                                                       \
    v2 _t;                                                                      \
    _t = vsel(_m,(lj),(li)); (lj) = vsel(_m,(li),(lj)); (li) = _t;              \
    _t = vsel(_m,(b0),(a0)); (b0) = vsel(_m,(a0),(b0)); (a0) = _t;              \
    _t = vsel(_m,(b1),(a1)); (b1) = vsel(_m,(a1),(b1)); (a1) = _t;              \
    _t = vsel(_m,(b2),(a2)); (b2) = vsel(_m,(a2),(b2)); (a2) = _t;              \
  } while (0)

__global__ __launch_bounds__(TPB) void plastic_svd_kernel(
    const float* __restrict__ F,
    const float* __restrict__ p_yml,
    const float* __restrict__ p_nu,
    const float* __restrict__ p_ys,
    float* __restrict__ out,
    int nmat)
{
  __shared__ float lds[CH_F];                // 4.6 KB/WG
  const int tid = threadIdx.x;
  const int blockBase = blockIdx.x * CHUNK;
  const int gbase = blockBase * 9;
  const int rem = nmat - blockBase;
  const int nfl = (rem >= CHUNK ? CHUNK : rem) * 9;
  const int nfl4 = nfl >> 2;

  // coalesced global -> LDS stage, float4-wide (gbase*4 bytes is 16B-aligned;
  // 64 lanes x 16B = 1KB contiguous per instruction -- R5 lesson: coalescing
  // is non-negotiable, AoS 72B/thread loads choke the TA).
  {
    const float4* g4 = (const float4*)(F + gbase);
    float4* l4 = (float4*)lds;
    #pragma unroll
    for (int k = 0; k < 5; ++k) {            // 5*64 = 320 >= 288
      int i4 = k * TPB + tid;
      if (i4 < CH_F4 && i4 < nfl4) l4[i4] = g4[i4];
    }
    int i = (nfl & ~3) + tid;
    if (i < nfl) lds[i] = F[gbase + i];      // scalar tail (<=3 elems)
    // zero-fill inactive tail (last block only): NaN-free with 1e-30 clamps
    for (int i2 = nfl + tid; i2 < CH_F; i2 += TPB) lds[i2] = 0.0f;
  }
  __syncthreads();   // single-wave WG: waitcnt fence only, no real barrier

  const int mi0 = blockBase + tid;           // lane .x matrix
  const int mi1 = blockBase + TPB + tid;     // lane .y matrix
  const float* mA = &lds[tid * 9];           // stride-9: 2 lanes/bank, free
  const float* mB = &lds[(TPB + tid) * 9];

  // ---- S = F^T F from LDS; F regs die after (VGPR relief in Jacobi) ----
  v2 s00, s11, s22, s01, s02, s12;
  {
    v2 f00,f01,f02,f10,f11,f12,f20,f21,f22;
    f00.x=mA[0]; f01.x=mA[1]; f02.x=mA[2];
    f10.x=mA[3]; f11.x=mA[4]; f12.x=mA[5];
    f20.x=mA[6]; f21.x=mA[7]; f22.x=mA[8];
    f00.y=mB[0]; f01.y=mB[1]; f02.y=mB[2];
    f10.y=mB[3]; f11.y=mB[4]; f12.y=mB[5];
    f20.y=mB[6]; f21.y=mB[7]; f22.y=mB[8];
    s00 = f00*f00 + f10*f10 + f20*f20;
    s11 = f01*f01 + f11*f11 + f21*f21;
    s22 = f02*f02 + f12*f12 + f22*f22;
    s01 = f00*f01 + f10*f11 + f20*f21;
    s02 = f00*f02 + f10*f12 + f20*f22;
    s12 = f01*f02 + f11*f12 + f21*f22;
  }

  // uniform scalar parameters
  const float mu_s = __builtin_amdgcn_exp2f(p_yml[0] * 1.44269504f) *
                     __builtin_amdgcn_rcpf(2.0f * (1.0f + p_nu[0]));
  const float qy_s = p_ys[0] * 0.5f * __builtin_amdgcn_rcpf(mu_s);
  const v2 qy = V2(qy_s);

  v2 v00,v01,v02,v10,v11,v12,v20,v21,v22;
  v2 c, s;

  // ---- sweep 1, rot (0,1): V = I specialization ----
  jcs2(s00, s11, s01, c, s, s00, s11);
  { v2 pk = s02, qk = s12; s02 = c*pk - s*qk; s12 = s*pk + c*qk; }
  v00 = c;  v01 = s;
  v10 = -s; v11 = c;
  s01 = V2(0.0f);
  // ---- sweep 1, rot (0,2): col2 still e3, col0 = (v00,v10,0) ----
  jcs2(s00, s22, s02, c, s, s00, s22);
  { v2 pk = s01, qk = s12; s01 = c*pk - s*qk; s12 = s*pk + c*qk; }
  v02 = s * v00; v12 = s * v10; v22 = c;
  v00 = c * v00; v10 = c * v10; v20 = -s;
  v21 = V2(0.0f);
  s02 = V2(0.0f);
  // ---- sweep 1, rot (1,2) ----
  jrot(s11, s22, s12, s01, s02, v01, v11, v21, v02, v12, v22);
  // ---- sweep 2 ----
  jrot(s00, s11, s01, s02, s12, v00, v10, v20, v01, v11, v21);
  jrot(s00, s22, s02, s01, s12, v00, v10, v20, v02, v12, v22);
  jrot(s11, s22, s12, s01, s02, v01, v11, v21, v02, v12, v22);
  // ---- sweep 3 ----
  jrot(s00, s11, s01, s02, s12, v00, v10, v20, v01, v11, v21);
  jrot(s00, s22, s02, s01, s12, v00, v10, v20, v02, v12, v22);
  // final rot (1,2): couplings dead; diag still updated (closed form).
  jcs2(s11, s22, s12, c, s, s11, s22);
  { v2 v;
    v = v01; v01 = c*v - s*v02; v02 = s*v + c*v02;
    v = v11; v11 = c*v - s*v12; v12 = s*v + c*v12;
    v = v21; v21 = c*v - s*v22; v22 = s*v + c*v22; }

  // ---- sort eigenvalues descending (GS conditioning: R2 lesson) ----
  v2 l0 = s00, l1 = s11, l2 = s22;
  CSWAP(l0, l1, v00, v10, v20, v01, v11, v21);
  CSWAP(l1, l2, v01, v11, v21, v02, v12, v22);
  CSWAP(l0, l1, v00, v10, v20, v01, v11, v21);

  // ---- re-read F from LDS (own slots, still intact) ----
  v2 f00,f01,f02,f10,f11,f12,f20,f21,f22;
  f00.x=mA[0]; f01.x=mA[1]; f02.x=mA[2];
  f10.x=mA[3]; f11.x=mA[4]; f12.x=mA[5];
  f20.x=mA[6]; f21.x=mA[7]; f22.x=mA[8];
  f00.y=mB[0]; f01.y=mB[1]; f02.y=mB[2];
  f10.y=mB[3]; f11.y=mB[4]; f12.y=mB[5];
  f20.y=mB[6]; f21.y=mB[7]; f22.y=mB[8];

  // ---- U: u0 = Fv0/|Fv0|; u1 = GS; u2 = u0 x u1 (sign-fixed) ----
  v2 w0x = f00*v00 + f01*v10 + f02*v20;
  v2 w0y = f10*v00 + f11*v10 + f12*v20;
  v2 w0z = f20*v00 + f21*v10 + f22*v20;
  v2 n0sq = w0x*w0x + w0y*w0y + w0z*w0z;
  v2 inv0 = rsq2(vmax(n0sq, V2(1e-30f)));
  v2 u0x = w0x*inv0, u0y = w0y*inv0, u0z = w0z*inv0;

  v2 w1x = f00*v01 + f01*v11 + f02*v21;
  v2 w1y = f10*v01 + f11*v11 + f12*v21;
  v2 w1z = f20*v01 + f21*v11 + f22*v21;
  v2 n1sq_pre = w1x*w1x + w1y*w1y + w1z*w1z;  // = sigma1^2 (pre-GS)
  v2 d01 = w1x*u0x + w1y*u0y + w1z*u0z;
  w1x = w1x - d01*u0x; w1y = w1y - d01*u0y; w1z = w1z - d01*u0z;
  v2 n1sq = w1x*w1x + w1y*w1y + w1z*w1z;
  v2 inv1 = rsq2(vmax(n1sq, V2(1e-30f)));
  v2 u1x = w1x*inv1, u1y = w1y*inv1, u1z = w1z*inv1;

  v2 u2x = u0y*u1z - u0z*u1y;
  v2 u2y = u0z*u1x - u0x*u1z;
  v2 u2z = u0x*u1y - u0y*u1x;
  v2 w2x = f00*v02 + f01*v12 + f02*v22;
  v2 w2y = f10*v02 + f11*v12 + f12*v22;
  v2 w2z = f20*v02 + f21*v12 + f22*v22;
  v2 s2d = u2x*w2x + u2y*w2y + u2z*w2z;
  v2 sg = vcps(V2(1.0f), s2d);               // sign-fix for det(U)=+1
  v2 sig2 = vabs(s2d);
  u2x = u2x * sg; u2y = u2y * sg; u2z = u2z * sg;

  // ---- von-Mises return mapping, base-2 internally ----
  // max(sqrt(n),0.01) == sqrt(max(n,1e-4)) -> e = 0.5*log2(max(n,1e-4))
  v2 e0 = lg22(vmax(n0sq,     V2(1e-4f))) * 0.5f;
  v2 e1 = lg22(vmax(n1sq_pre, V2(1e-4f))) * 0.5f;
  v2 e2 = lg22(vmax(sig2,     V2(0.01f)));
  v2 m3 = (e0 + e1 + e2) * (1.0f / 3.0f);
  v2 b0 = e0 - m3, b1 = e1 - m3, b2 = e2 - m3;
  v2 bn = sqt2(b0*b0 + b1*b1 + b2*b2) * 0.69314718f + V2(1e-5f);
  v2 r = vmax(bn - qy, V2(0.0f)) * rcp2(bn);   // 0 if elastic
  v2 c0 = ex22(e0 - r * b0);
  v2 c1 = ex22(e1 - r * b1);
  v2 c2 = ex22(e2 - r * b2);

  // ---- out = sum_i c_i u_i v_i^T ----
  v2 a0x = c0*u0x, a0y = c0*u0y, a0z = c0*u0z;
  v2 a1x = c1*u1x, a1y = c1*u1y, a1z = c1*u1z;
  v2 a2x = c2*u2x, a2y = c2*u2y, a2z = c2*u2z;

  v2 o00 = a0x*v00 + a1x*v01 + a2x*v02;
  v2 o01 = a0x*v10 + a1x*v11 + a2x*v12;
  v2 o02 = a0x*v20 + a1x*v21 + a2x*v22;
  v2 o10 = a0y*v00 + a1y*v01 + a2y*v02;
  v2 o11 = a0y*v10 + a1y*v11 + a2y*v12;
  v2 o12 = a0y*v20 + a1y*v21 + a2y*v22;
  v2 o20 = a0z*v00 + a1z*v01 + a2z*v02;
  v2 o21 = a0z*v10 + a1z*v11 + a2z*v12;
  v2 o22 = a0z*v20 + a1z*v21 + a2z*v22;

  if (mi0 < nmat) {
    float* m = &lds[tid * 9];
    m[0]=o00.x; m[1]=o01.x; m[2]=o02.x;
    m[3]=o10.x; m[4]=o11.x; m[5]=o12.x;
    m[6]=o20.x; m[7]=o21.x; m[8]=o22.x;
  }
  if (mi1 < nmat) {
    float* m = &lds[(TPB + tid) * 9];
    m[0]=o00.y; m[1]=o01.y; m[2]=o02.y;
    m[3]=o10.y; m[4]=o11.y; m[5]=o12.y;
    m[6]=o20.y; m[7]=o21.y; m[8]=o22.y;
  }
  __syncthreads();   // in-wave ordering fence (ds in-order; compiler fence)

  // coalesced LDS -> global store, float4-wide
  {
    float4* g4 = (float4*)(out + gbase);
    const float4* l4 = (const float4*)lds;
    #pragma unroll
    for (int k = 0; k < 5; ++k) {
      int i4 = k * TPB + tid;
      if (i4 < CH_F4 && i4 < nfl4) g4[i4] = l4[i4];
    }
    int i = (nfl & ~3) + tid;
    if (i < nfl) out[gbase + i] = lds[i];
  }
}

extern "C" void kernel_launch(void* const* d_in, const int* in_sizes, int n_in,
                              void* d_out, int out_size, void* d_ws, size_t ws_size,
                              hipStream_t stream) {
  const float* F     = (const float*)d_in[0];
  const float* p_yml = (const float*)d_in[1];
  const float* p_nu  = (const float*)d_in[2];
  const float* p_ys  = (const float*)d_in[3];
  float* out = (float*)d_out;

  const int nmat = in_sizes[0] / 9;
  const int nblocks = (nmat + CHUNK - 1) / CHUNK;
  hipLaunchKernelGGL(plastic_svd_kernel, dim3(nblocks), dim3(TPB), 0, stream,
                     F, p_yml, p_nu, p_ys, out, nmat);
}